// Round 13
// baseline (338.323 us; speedup 1.0000x reference)
//
#include <hip/hip_runtime.h>
#include <cstdint>
#include <cstddef>

#define S_LEN 2048
#define DIM_   2048
#define NH   16
#define NKV  8
#define HD   128

typedef __attribute__((ext_vector_type(8))) __bf16 bf16x8;
typedef __attribute__((ext_vector_type(4))) float  f32x4;

typedef const __attribute__((address_space(1))) void* gptr_t;
typedef __attribute__((address_space(3))) void*       sptr_t;

static __device__ __forceinline__ float bf2f(unsigned short u) {
  union { unsigned int i; float f; } v; v.i = ((unsigned int)u) << 16; return v.f;
}
static __device__ __forceinline__ unsigned short f2bf(float f) {
  union { float f; unsigned int i; } v; v.f = f;
  unsigned int u = v.i;
  unsigned int r = (u + 0x7FFFu + ((u >> 16) & 1u)) >> 16;
  return (unsigned short)r;
}
// packed f32x2 -> bf16x2 (RNE), single instruction (T12 primitive)
static __device__ __forceinline__ unsigned int cvt_pk_bf16(float a, float b) {
  unsigned int r;
  asm volatile("v_cvt_pk_bf16_f32 %0, %1, %2" : "=v"(r) : "v"(a), "v"(b));
  return r;
}

// scale(1/sqrt(128)) * log2(e) — folded into q so softmax uses exp2 directly
#define QSCALE 0.12751744f
// defer-max threshold (T13): 8 in ln-domain -> 8*log2(e) in exp2-domain
#define RESC_THR 11.542f

// ---------------- prep: x->bf16 convert + 4 weight transpose-converts ----------------
// 64x64 tiles, float4 loads + packed ushort4 stores (round-7, proven).
__global__ void k_prep(const float* __restrict__ x, unsigned short* __restrict__ xb,
                       const float* __restrict__ wq, const float* __restrict__ wk,
                       const float* __restrict__ wv, const float* __restrict__ wo,
                       unsigned short* __restrict__ wqkvT, unsigned short* __restrict__ woT) {
  int bid = blockIdx.x;
  if (bid < 8192) {
    int i = bid * 256 + threadIdx.x;
    float4 v = ((const float4*)x)[i];
    ushort4 o; o.x = f2bf(v.x); o.y = f2bf(v.y); o.z = f2bf(v.z); o.w = f2bf(v.w);
    ((ushort4*)xb)[i] = o;
    return;
  }
  bid -= 8192;
  const float* src; unsigned short* dst; int N, ntx;
  if (bid < 1024)      { src = wq; dst = wqkvT;                       N = 2048; ntx = 32; }
  else if (bid < 1536) { bid -= 1024; src = wk; dst = wqkvT + (size_t)2048 * 2048; N = 1024; ntx = 16; }
  else if (bid < 2048) { bid -= 1536; src = wv; dst = wqkvT + (size_t)3072 * 2048; N = 1024; ntx = 16; }
  else                 { bid -= 2048; src = wo; dst = woT;            N = 2048; ntx = 32; }
  const int K = 2048;
  __shared__ float tile[64][65];
  int lx = threadIdx.x & 15, ly = threadIdx.x >> 4;  // 16 x 16
  int r0 = (bid / ntx) * 64, c0 = (bid % ntx) * 64;
  #pragma unroll
  for (int i = 0; i < 4; i++) {
    int row = ly + 16 * i;
    float4 v = *(const float4*)(&src[(size_t)(r0 + row) * N + c0 + lx * 4]);
    tile[row][lx * 4 + 0] = v.x; tile[row][lx * 4 + 1] = v.y;
    tile[row][lx * 4 + 2] = v.z; tile[row][lx * 4 + 3] = v.w;
  }
  __syncthreads();
  #pragma unroll
  for (int i = 0; i < 4; i++) {
    int nrow = ly + 16 * i;
    ushort4 o;
    o.x = f2bf(tile[lx * 4 + 0][nrow]); o.y = f2bf(tile[lx * 4 + 1][nrow]);
    o.z = f2bf(tile[lx * 4 + 2][nrow]); o.w = f2bf(tile[lx * 4 + 3][nrow]);
    *(ushort4*)(&dst[(size_t)(c0 + nrow) * K + r0 + lx * 4]) = o;
  }
}

// ------------- GEMM: C(MxN) = A(MxK) * BT(NxK)^T, bf16 in, fp32 acc -------------
// PROVEN 2-barrier template, generalized over <MODE, BM_, TPB>.
// BK=64, XOR-swizzled LDS via source permutation (bank-conflict 0 measured).
// TILE-SPACE MEASURED (MODE3): 128sq @4/CU = 84-87us BEST; 256x128 @2/CU = 100;
// 256sq @1/CU piped = 123. TLP dominates tile density in this structure.
template<int MODE, int BM_, int TPB>
__global__ __launch_bounds__(TPB, 2) void k_gemm_bt(
    const unsigned short* __restrict__ A, const unsigned short* __restrict__ BT,
    void* __restrict__ C, int N, int K,
    const float* __restrict__ fc, const float* __restrict__ fs,
    unsigned short* __restrict__ kb, unsigned short* __restrict__ vb) {
  constexpr int NI = (BM_ == 64) ? 2 : 4;          // B-frags per wave
  constexpr int AR = (BM_ * 64) / (TPB * 8);       // A staging rounds
  constexpr int BR = (128 * 64) / (TPB * 8);       // B staging rounds
  __shared__ __align__(16) unsigned short Asm[BM_ * 64];
  __shared__ __align__(16) unsigned short Bsm[128 * 64];
  const int t = threadIdx.x;
  const int lane = t & 63, w = t >> 6;
  const int wm = (BM_ == 64) ? 0 : (w >> 1) * 64;
  const int wn = (BM_ == 64) ? w * 32 : (w & 1) * 64;
  const int col = lane & 15, quad = lane >> 4;
  const int m0 = blockIdx.y * BM_, n0 = blockIdx.x * 128;

  f32x4 acc[4][NI];
  #pragma unroll
  for (int i = 0; i < 4; i++)
    #pragma unroll
    for (int j = 0; j < NI; j++) acc[i][j] = (f32x4){0.f, 0.f, 0.f, 0.f};

  for (int kk = 0; kk < K; kk += 64) {
    #pragma unroll
    for (int r = 0; r < AR; ++r) {   // A: BM_ rows x 64
      int c = t + r * TPB;
      int c0 = (t & ~63) + r * TPB;   // wave-uniform chunk base
      int row = c >> 3;
      int kcs = (c & 7) ^ (row & 7);  // source permutation = target swizzle
      const unsigned short* gA = A + (size_t)(m0 + row) * K + kk + kcs * 8;
      __builtin_amdgcn_global_load_lds((gptr_t)gA, (sptr_t)(&Asm[c0 * 8]), 16, 0, 0);
    }
    #pragma unroll
    for (int r = 0; r < BR; ++r) {   // B: 128 rows x 64
      int c = t + r * TPB;
      int c0 = (t & ~63) + r * TPB;
      int row = c >> 3;
      int kcs = (c & 7) ^ (row & 7);
      const unsigned short* gB = BT + (size_t)(n0 + row) * K + kk + kcs * 8;
      __builtin_amdgcn_global_load_lds((gptr_t)gB, (sptr_t)(&Bsm[c0 * 8]), 16, 0, 0);
    }
    __syncthreads();
    #pragma unroll
    for (int kc2 = 0; kc2 < 2; kc2++) {
      bf16x8 af[4], bf[NI];
      #pragma unroll
      for (int mi = 0; mi < 4; mi++) {
        int rowA = wm + mi * 16 + col;
        af[mi] = *(const bf16x8*)(&Asm[rowA * 64 + (((kc2 * 4 + quad) ^ (col & 7)) * 8)]);
      }
      #pragma unroll
      for (int ni = 0; ni < NI; ni++) {
        int rowB = wn + ni * 16 + col;
        bf[ni] = *(const bf16x8*)(&Bsm[rowB * 64 + (((kc2 * 4 + quad) ^ (col & 7)) * 8)]);
      }
      #pragma unroll
      for (int mi = 0; mi < 4; mi++)
        #pragma unroll
        for (int ni = 0; ni < NI; ni++)
          acc[mi][ni] = __builtin_amdgcn_mfma_f32_16x16x32_bf16(af[mi], bf[ni], acc[mi][ni], 0, 0, 0);
    }
    __syncthreads();
  }

  #pragma unroll
  for (int mi = 0; mi < 4; mi++) {
    int row_base = m0 + wm + mi * 16 + quad * 4;
    #pragma unroll
    for (int ni = 0; ni < NI; ni++) {
      int col_g = n0 + wn + ni * 16 + col;
      if (MODE == 1) {
        float* O = (float*)C;
        #pragma unroll
        for (int r = 0; r < 4; r++) O[(size_t)(row_base + r) * N + col_g] = acc[mi][ni][r];
      } else {  // MODE 3
        int region = col_g >> 10;  // 0,1: q ; 2: k ; 3: v
        if (region < 3) {
          int ri = (col_g & 127) >> 1;
          float sgn = (col_g & 1) ? 1.f : -1.f;
          unsigned short* qO = (unsigned short*)C;
          #pragma unroll
          for (int r = 0; r < 4; r++) {
            int row = row_base + r;
            int s = row & (S_LEN - 1);
            float cv = fc[s * 64 + ri], sv = fs[s * 64 + ri];
            float val = acc[mi][ni][r];
            float other = __shfl_xor(val, 1);
            float res = val * cv + sgn * other * sv;
            if (region < 2) qO[(size_t)row * 2048 + col_g] = f2bf(res * QSCALE);
            else            kb[(size_t)row * 1024 + (col_g - 2048)] = f2bf(res);
          }
        } else {
          int n_local = col_g - 3072;
          int b = row_base >> 11, s = row_base & (S_LEN - 1);
          int kvh = n_local >> 7, d = n_local & (HD - 1);
          ushort4 o4;
          o4.x = f2bf(acc[mi][ni][0]); o4.y = f2bf(acc[mi][ni][1]);
          o4.z = f2bf(acc[mi][ni][2]); o4.w = f2bf(acc[mi][ni][3]);
          *(ushort4*)(&vb[((size_t)((b * NKV + kvh) * HD + d)) * S_LEN + s]) = o4;
        }
      }
    }
  }
}

// ---------------- Flash attention, causal, GQA K/V ----------------
// ROUND-13: DOUBLE-BUFFERED K/V -> ONE barrier per tile (was 2).
// Rationale: round 12 showed 3 blocks/CU ~= 2 blocks/CU (domain count is not
// the limiter); per-tile work is ~500 cy but tile rate is several thousand cy
// -> the 2x per-tile __syncthreads (each = vmcnt(0)+lgkmcnt(0) drain + sync)
// plus the K/V-write window squeezed between them is the prime suspect.
// Ping-pong invariant: iteration t READS buf[t&1], WRITES buf[(t+1)&1] --
// disjoint buffers, so one end-of-iteration barrier provides both visibility
// (writes of t+1 before readers of t+1) and WAR safety (no wave can still be
// in iteration t-1 past that barrier). LDS 80896 B -> 2 blocks/CU.
// 256-thread blocks (4 waves), ONE (b,h,q-tile) per block, grid (32,32),
// long-first dispatch. Kept: swapped QK^T, async early-issue loads (T14,
// NAMED scalars per rule #20 / round-11 lesson), defer-max (T13), setprio
// (T5), cvt_pk P-packing, speculative exp2, strength-reduced pointers.
// ROUND-8 LESSON: PLD multiple of 8. ROUND-9 LESSON: linear layouts are at
// the bank floor; do not swizzle. Guard: WRITE_SIZE ~16 MB (spill detector).
#define KLD 136   // 128 + 8
#define VLD 72    // 64 + 8
#define PLD 72    // multiple of 8
__global__ __launch_bounds__(256, 2) void k_attn(
    const unsigned short* __restrict__ q, const unsigned short* __restrict__ k,
    const unsigned short* __restrict__ vT, unsigned short* __restrict__ ao) {
  __shared__ __align__(16) unsigned short Ksm[2][64 * KLD];    // 34816 B
  __shared__ __align__(16) unsigned short Vsm[2][128 * VLD];   // 36864 B
  __shared__ __align__(16) unsigned short Psm[4 * 16 * PLD];   //  9216 B
  const int t = threadIdx.x;
  const int lane = t & 63, w = t >> 6;        // 4 waves
  const int col = lane & 15, quad = lane >> 4;
  const int bh = blockIdx.x;                  // b*NH + h
  const int b = bh >> 4, h = bh & 15;
  const int kvh = h >> 1;
  const int my_qt = 31 - blockIdx.y;          // long blocks launch FIRST
  const int qrow = my_qt * 64 + w * 16;       // this wave's 16 query rows
  unsigned short* Pw = &Psm[w * 16 * PLD];

  // staging: 4 uint4 per thread per matrix (256 threads)
  const int ki = t >> 4, kdc = t & 15;        // K row (+cc*16) / d-chunk
  const int vd = t >> 3, vkc = t & 7;         // V d-row (+cc*32) / key-chunk
  const unsigned short* kg = k + ((size_t)(b * S_LEN + ki)) * (NKV * HD) + kvh * HD + kdc * 8;
  const unsigned short* vg = vT + ((size_t)((b * NKV + kvh) * HD + vd)) * S_LEN + vkc * 8;
  const size_t KROW = (size_t)16 * (NKV * HD);    // +16 K rows
  const size_t VROW = (size_t)32 * S_LEN;         // +32 V d-rows
  const size_t KSTEP = (size_t)64 * (NKV * HD);   // shorts per K-tile
  const size_t VSTEP = 64;                        // shorts per V-tile

  bf16x8 qf[4];
  const size_t qbase = ((size_t)(b * S_LEN) + qrow + col) * DIM_ + h * HD;
  #pragma unroll
  for (int kc = 0; kc < 4; kc++) qf[kc] = *(const bf16x8*)(q + qbase + kc * 32 + quad * 8);

  f32x4 o[8];
  #pragma unroll
  for (int i = 0; i < 8; i++) o[i] = (f32x4){0.f, 0.f, 0.f, 0.f};
  float m_i = -1e30f;   // running max for q-row (qrow + col)
  float l_i = 0.f;      // running denom

  const int nkt = my_qt + 1;                  // block-uniform causal range

  // prologue: stage tile 0 into buffer 0
  {
    #pragma unroll
    for (int cc = 0; cc < 4; cc++) {
      uint4 kr = *(const uint4*)(kg + cc * KROW);
      *(uint4*)(&Ksm[0][(ki + cc * 16) * KLD + kdc * 8]) = kr;
      uint4 vr = *(const uint4*)(vg + cc * VROW);
      *(uint4*)(&Vsm[0][(vd + cc * 32) * VLD + vkc * 8]) = vr;
    }
  }
  __syncthreads();

  for (int kt = 0; kt < nkt; ++kt) {
    const int cur = kt & 1, nxt = cur ^ 1;
    const bool more = (kt + 1 < nkt);         // block-uniform
    // NAMED scalars (rule #20: arrays here get demoted to scratch)
    uint4 kr0, kr1, kr2, kr3, vr0, vr1, vr2, vr3;
    if (more) {                               // issue ALL t+1 loads early
      kg += KSTEP; vg += VSTEP;
      kr0 = *(const uint4*)(kg + 0 * KROW);
      kr1 = *(const uint4*)(kg + 1 * KROW);
      kr2 = *(const uint4*)(kg + 2 * KROW);
      kr3 = *(const uint4*)(kg + 3 * KROW);
      vr0 = *(const uint4*)(vg + 0 * VROW);
      vr1 = *(const uint4*)(vg + 1 * VROW);
      vr2 = *(const uint4*)(vg + 2 * VROW);
      vr3 = *(const uint4*)(vg + 3 * VROW);
    }

    // ---- QK^T, swapped operands: p[nt][r] = P[key = kt*64+nt*16+quad*4+r][q = col]
    float p[4][4];
    __builtin_amdgcn_s_setprio(1);
    #pragma unroll
    for (int nt = 0; nt < 4; nt++) {
      f32x4 s_acc = (f32x4){0.f, 0.f, 0.f, 0.f};
      #pragma unroll
      for (int kc = 0; kc < 4; kc++) {
        bf16x8 kf = *(const bf16x8*)(&Ksm[cur][(nt * 16 + col) * KLD + kc * 32 + quad * 8]);
        s_acc = __builtin_amdgcn_mfma_f32_16x16x32_bf16(kf, qf[kc], s_acc, 0, 0, 0);
      }
      #pragma unroll
      for (int r = 0; r < 4; r++) p[nt][r] = s_acc[r];
    }
    __builtin_amdgcn_s_setprio(0);

    if (kt == my_qt) {  // diagonal tile: causal mask
      const int qglob = qrow + col;
      #pragma unroll
      for (int nt = 0; nt < 4; nt++)
        #pragma unroll
        for (int r = 0; r < 4; r++)
          if (kt * 64 + nt * 16 + quad * 4 + r > qglob) p[nt][r] = -1e30f;
    }

    // ---- softmax, speculative: exp2 with OLD m_i runs during the max shuffles
    float mx = fmaxf(fmaxf(fmaxf(p[0][0], p[0][1]), fmaxf(p[0][2], p[0][3])),
                     fmaxf(fmaxf(p[1][0], p[1][1]), fmaxf(p[1][2], p[1][3])));
    mx = fmaxf(mx, fmaxf(fmaxf(fmaxf(p[2][0], p[2][1]), fmaxf(p[2][2], p[2][3])),
                         fmaxf(fmaxf(p[3][0], p[3][1]), fmaxf(p[3][2], p[3][3]))));
    float mxs = fmaxf(mx, __shfl_xor(mx, 16));
    mxs = fmaxf(mxs, __shfl_xor(mxs, 32));
    float pe[4][4];
    #pragma unroll
    for (int nt = 0; nt < 4; nt++)
      #pragma unroll
      for (int r = 0; r < 4; r++) pe[nt][r] = exp2f(p[nt][r] - m_i);
    float rs = ((pe[0][0] + pe[0][1]) + (pe[0][2] + pe[0][3]))
             + ((pe[1][0] + pe[1][1]) + (pe[1][2] + pe[1][3]))
             + ((pe[2][0] + pe[2][1]) + (pe[2][2] + pe[2][3]))
             + ((pe[3][0] + pe[3][1]) + (pe[3][2] + pe[3][3]));
    if (__any(mxs - m_i > RESC_THR)) {   // rare: first tile + big max growth
      float mn = fmaxf(m_i, mxs);
      float alpha = exp2f(m_i - mn);
      m_i = mn; l_i *= alpha;
      float ar[4];
      #pragma unroll
      for (int r = 0; r < 4; r++) ar[r] = __shfl(alpha, quad * 4 + r);
      #pragma unroll
      for (int dt = 0; dt < 8; dt++)
        #pragma unroll
        for (int r = 0; r < 4; r++) o[dt][r] *= ar[r];
      #pragma unroll
      for (int nt = 0; nt < 4; nt++)
        #pragma unroll
        for (int r = 0; r < 4; r++) pe[nt][r] = exp2f(p[nt][r] - m_i);
      rs = ((pe[0][0] + pe[0][1]) + (pe[0][2] + pe[0][3]))
         + ((pe[1][0] + pe[1][1]) + (pe[1][2] + pe[1][3]))
         + ((pe[2][0] + pe[2][1]) + (pe[2][2] + pe[2][3]))
         + ((pe[3][0] + pe[3][1]) + (pe[3][2] + pe[3][3]));
    }
    rs += __shfl_xor(rs, 16);
    rs += __shfl_xor(rs, 32);
    l_i += rs;

    // ---- P -> Pw (A-layout: Pw[q][key]), cvt_pk pairs + uint2 writes
    #pragma unroll
    for (int nt = 0; nt < 4; nt++) {
      uint2 pk;
      pk.x = cvt_pk_bf16(pe[nt][0], pe[nt][1]);
      pk.y = cvt_pk_bf16(pe[nt][2], pe[nt][3]);
      *(uint2*)(&Pw[col * PLD + nt * 16 + quad * 4]) = pk;
    }
    asm volatile("s_waitcnt lgkmcnt(0)" ::: "memory");  // wave-internal RAW
    bf16x8 pf[2];
    #pragma unroll
    for (int kc2 = 0; kc2 < 2; kc2++)
      pf[kc2] = *(const bf16x8*)(&Pw[col * PLD + kc2 * 32 + quad * 8]);

    // ---- O += P V (reads Vsm[cur])
    __builtin_amdgcn_s_setprio(1);
    #pragma unroll
    for (int dt = 0; dt < 8; dt++) {
      #pragma unroll
      for (int kc2 = 0; kc2 < 2; kc2++) {
        bf16x8 vf = *(const bf16x8*)(&Vsm[cur][(dt * 16 + col) * VLD + kc2 * 32 + quad * 8]);
        o[dt] = __builtin_amdgcn_mfma_f32_16x16x32_bf16(pf[kc2], vf, o[dt], 0, 0, 0);
      }
    }
    __builtin_amdgcn_s_setprio(0);

    // ---- stage tile t+1 into the OTHER buffers (no wave reads them until
    //      after the barrier below; no wave is still in iteration t-1)
    if (more) {
      *(uint4*)(&Ksm[nxt][(ki +  0) * KLD + kdc * 8]) = kr0;
      *(uint4*)(&Ksm[nxt][(ki + 16) * KLD + kdc * 8]) = kr1;
      *(uint4*)(&Ksm[nxt][(ki + 32) * KLD + kdc * 8]) = kr2;
      *(uint4*)(&Ksm[nxt][(ki + 48) * KLD + kdc * 8]) = kr3;
      *(uint4*)(&Vsm[nxt][(vd +  0) * VLD + vkc * 8]) = vr0;
      *(uint4*)(&Vsm[nxt][(vd + 32) * VLD + vkc * 8]) = vr1;
      *(uint4*)(&Vsm[nxt][(vd + 64) * VLD + vkc * 8]) = vr2;
      *(uint4*)(&Vsm[nxt][(vd + 96) * VLD + vkc * 8]) = vr3;
    }

    __syncthreads();   // ONE barrier per tile: publishes buf[nxt], retires buf[cur]
  }

  // epilogue: 1/l for this lane's four q-rows (col -> row permute, once)
  float linv[4];
  #pragma unroll
  for (int r = 0; r < 4; r++) linv[r] = 1.f / __shfl(l_i, quad * 4 + r);
  #pragma unroll
  for (int dt = 0; dt < 8; dt++) {
    int dcol = h * HD + dt * 16 + col;
    #pragma unroll
    for (int r = 0; r < 4; r++) {
      int rg = qrow + quad * 4 + r;
      ao[((size_t)(b * S_LEN) + rg) * DIM_ + dcol] = f2bf(o[dt][r] * linv[r]);
    }
  }
}

extern "C" void kernel_launch(void* const* d_in, const int* in_sizes, int n_in,
                              void* d_out, int out_size, void* d_ws, size_t ws_size,
                              hipStream_t stream) {
  const float* x  = (const float*)d_in[0];
  const float* fc = (const float*)d_in[1];
  const float* fs = (const float*)d_in[2];
  const float* wq = (const float*)d_in[3];
  const float* wk = (const float*)d_in[4];
  const float* wv = (const float*)d_in[5];
  const float* wo = (const float*)d_in[6];
  float* out = (float*)d_out;

  char* ws = (char*)d_ws;
  const size_t MB = 1024 * 1024;
  unsigned short* xb    = (unsigned short*)(ws + 0 * MB);    // 4096x2048 bf16 (16 MiB)
  unsigned short* wqkvT = (unsigned short*)(ws + 16 * MB);   // 4096x2048      (16 MiB)
  unsigned short* woT   = (unsigned short*)(ws + 32 * MB);   // 2048x2048      (8 MiB)
  unsigned short* qb    = (unsigned short*)(ws + 40 * MB);   // 4096x2048      (16 MiB)
  unsigned short* kb    = (unsigned short*)(ws + 56 * MB);   // 4096x1024      (8 MiB)
  unsigned short* vT    = (unsigned short*)(ws + 64 * MB);   // (b,kvh,d,s)    (8 MiB)
  unsigned short* ao    = (unsigned short*)(ws + 72 * MB);   // 4096x2048      (16 MiB)

  // prep: convert x + transpose-convert all weights (vectorized 64x64 transpose)
  k_prep<<<dim3(11264), dim3(256), 0, stream>>>(x, xb, wq, wk, wv, wo, wqkvT, woT);
  // fused QKV projection + RoPE (+q pre-scale) + V transpose: 128sq, 4 blocks/CU (proven best)
  k_gemm_bt<3, 128, 256><<<dim3(32, 32), dim3(256), 0, stream>>>(xb, wqkvT, (void*)qb, 4096, 2048, fc, fs, kb, vT);
  // attention: double-buffered K/V, ONE barrier per tile, 2 blocks/CU
  k_attn<<<dim3(32, 32), dim3(256), 0, stream>>>(qb, kb, vT, ao);
  // output projection (f32 out): 64x128 tiles -> grid (16,64) = 4 blocks/CU (round-4 proven)
  k_gemm_bt<1, 64, 256><<<dim3(16, 64), dim3(256), 0, stream>>>(ao, woT, (void*)out, 2048, 2048, nullptr, nullptr, nullptr, nullptr);
}

// Round 14
// 337.420 us; speedup vs baseline: 1.0027x; 1.0027x over previous
//
#include <hip/hip_runtime.h>
#include <cstdint>
#include <cstddef>

#define S_LEN 2048
#define DIM_   2048
#define NH   16
#define NKV  8
#define HD   128

typedef __attribute__((ext_vector_type(8))) __bf16 bf16x8;
typedef __attribute__((ext_vector_type(4))) float  f32x4;

typedef const __attribute__((address_space(1))) void* gptr_t;
typedef __attribute__((address_space(3))) void*       sptr_t;

static __device__ __forceinline__ float bf2f(unsigned short u) {
  union { unsigned int i; float f; } v; v.i = ((unsigned int)u) << 16; return v.f;
}
static __device__ __forceinline__ unsigned short f2bf(float f) {
  union { float f; unsigned int i; } v; v.f = f;
  unsigned int u = v.i;
  unsigned int r = (u + 0x7FFFu + ((u >> 16) & 1u)) >> 16;
  return (unsigned short)r;
}
// packed f32x2 -> bf16x2 (RNE), single instruction (T12 primitive)
static __device__ __forceinline__ unsigned int cvt_pk_bf16(float a, float b) {
  unsigned int r;
  asm volatile("v_cvt_pk_bf16_f32 %0, %1, %2" : "=v"(r) : "v"(a), "v"(b));
  return r;
}

// scale(1/sqrt(128)) * log2(e) — folded into q so softmax uses exp2 directly
#define QSCALE 0.12751744f
// defer-max threshold (T13): 8 in ln-domain -> 8*log2(e) in exp2-domain
#define RESC_THR 11.542f

// ---------------- prep: x->bf16 convert + 4 weight transpose-converts ----------------
// 64x64 tiles, float4 loads + packed ushort4 stores (round-7, proven).
__global__ void k_prep(const float* __restrict__ x, unsigned short* __restrict__ xb,
                       const float* __restrict__ wq, const float* __restrict__ wk,
                       const float* __restrict__ wv, const float* __restrict__ wo,
                       unsigned short* __restrict__ wqkvT, unsigned short* __restrict__ woT) {
  int bid = blockIdx.x;
  if (bid < 8192) {
    int i = bid * 256 + threadIdx.x;
    float4 v = ((const float4*)x)[i];
    ushort4 o; o.x = f2bf(v.x); o.y = f2bf(v.y); o.z = f2bf(v.z); o.w = f2bf(v.w);
    ((ushort4*)xb)[i] = o;
    return;
  }
  bid -= 8192;
  const float* src; unsigned short* dst; int N, ntx;
  if (bid < 1024)      { src = wq; dst = wqkvT;                       N = 2048; ntx = 32; }
  else if (bid < 1536) { bid -= 1024; src = wk; dst = wqkvT + (size_t)2048 * 2048; N = 1024; ntx = 16; }
  else if (bid < 2048) { bid -= 1536; src = wv; dst = wqkvT + (size_t)3072 * 2048; N = 1024; ntx = 16; }
  else                 { bid -= 2048; src = wo; dst = woT;            N = 2048; ntx = 32; }
  const int K = 2048;
  __shared__ float tile[64][65];
  int lx = threadIdx.x & 15, ly = threadIdx.x >> 4;  // 16 x 16
  int r0 = (bid / ntx) * 64, c0 = (bid % ntx) * 64;
  #pragma unroll
  for (int i = 0; i < 4; i++) {
    int row = ly + 16 * i;
    float4 v = *(const float4*)(&src[(size_t)(r0 + row) * N + c0 + lx * 4]);
    tile[row][lx * 4 + 0] = v.x; tile[row][lx * 4 + 1] = v.y;
    tile[row][lx * 4 + 2] = v.z; tile[row][lx * 4 + 3] = v.w;
  }
  __syncthreads();
  #pragma unroll
  for (int i = 0; i < 4; i++) {
    int nrow = ly + 16 * i;
    ushort4 o;
    o.x = f2bf(tile[lx * 4 + 0][nrow]); o.y = f2bf(tile[lx * 4 + 1][nrow]);
    o.z = f2bf(tile[lx * 4 + 2][nrow]); o.w = f2bf(tile[lx * 4 + 3][nrow]);
    *(ushort4*)(&dst[(size_t)(c0 + nrow) * K + r0 + lx * 4]) = o;
  }
}

// ------------- GEMM: C(MxN) = A(MxK) * BT(NxK)^T, bf16 in, fp32 acc -------------
// PROVEN 2-barrier template, generalized over <MODE, BM_, TPB>.
// BK=64, XOR-swizzled LDS via source permutation (bank-conflict 0 measured).
// TILE-SPACE MEASURED (MODE3): 128sq @4/CU = 84-87us BEST; 256x128 @2/CU = 100;
// 256sq @1/CU piped = 123. TLP dominates tile density in this structure.
template<int MODE, int BM_, int TPB>
__global__ __launch_bounds__(TPB, 2) void k_gemm_bt(
    const unsigned short* __restrict__ A, const unsigned short* __restrict__ BT,
    void* __restrict__ C, int N, int K,
    const float* __restrict__ fc, const float* __restrict__ fs,
    unsigned short* __restrict__ kb, unsigned short* __restrict__ vb) {
  constexpr int NI = (BM_ == 64) ? 2 : 4;          // B-frags per wave
  constexpr int AR = (BM_ * 64) / (TPB * 8);       // A staging rounds
  constexpr int BR = (128 * 64) / (TPB * 8);       // B staging rounds
  __shared__ __align__(16) unsigned short Asm[BM_ * 64];
  __shared__ __align__(16) unsigned short Bsm[128 * 64];
  const int t = threadIdx.x;
  const int lane = t & 63, w = t >> 6;
  const int wm = (BM_ == 64) ? 0 : (w >> 1) * 64;
  const int wn = (BM_ == 64) ? w * 32 : (w & 1) * 64;
  const int col = lane & 15, quad = lane >> 4;
  const int m0 = blockIdx.y * BM_, n0 = blockIdx.x * 128;

  f32x4 acc[4][NI];
  #pragma unroll
  for (int i = 0; i < 4; i++)
    #pragma unroll
    for (int j = 0; j < NI; j++) acc[i][j] = (f32x4){0.f, 0.f, 0.f, 0.f};

  for (int kk = 0; kk < K; kk += 64) {
    #pragma unroll
    for (int r = 0; r < AR; ++r) {   // A: BM_ rows x 64
      int c = t + r * TPB;
      int c0 = (t & ~63) + r * TPB;   // wave-uniform chunk base
      int row = c >> 3;
      int kcs = (c & 7) ^ (row & 7);  // source permutation = target swizzle
      const unsigned short* gA = A + (size_t)(m0 + row) * K + kk + kcs * 8;
      __builtin_amdgcn_global_load_lds((gptr_t)gA, (sptr_t)(&Asm[c0 * 8]), 16, 0, 0);
    }
    #pragma unroll
    for (int r = 0; r < BR; ++r) {   // B: 128 rows x 64
      int c = t + r * TPB;
      int c0 = (t & ~63) + r * TPB;
      int row = c >> 3;
      int kcs = (c & 7) ^ (row & 7);
      const unsigned short* gB = BT + (size_t)(n0 + row) * K + kk + kcs * 8;
      __builtin_amdgcn_global_load_lds((gptr_t)gB, (sptr_t)(&Bsm[c0 * 8]), 16, 0, 0);
    }
    __syncthreads();
    #pragma unroll
    for (int kc2 = 0; kc2 < 2; kc2++) {
      bf16x8 af[4], bf[NI];
      #pragma unroll
      for (int mi = 0; mi < 4; mi++) {
        int rowA = wm + mi * 16 + col;
        af[mi] = *(const bf16x8*)(&Asm[rowA * 64 + (((kc2 * 4 + quad) ^ (col & 7)) * 8)]);
      }
      #pragma unroll
      for (int ni = 0; ni < NI; ni++) {
        int rowB = wn + ni * 16 + col;
        bf[ni] = *(const bf16x8*)(&Bsm[rowB * 64 + (((kc2 * 4 + quad) ^ (col & 7)) * 8)]);
      }
      #pragma unroll
      for (int mi = 0; mi < 4; mi++)
        #pragma unroll
        for (int ni = 0; ni < NI; ni++)
          acc[mi][ni] = __builtin_amdgcn_mfma_f32_16x16x32_bf16(af[mi], bf[ni], acc[mi][ni], 0, 0, 0);
    }
    __syncthreads();
  }

  #pragma unroll
  for (int mi = 0; mi < 4; mi++) {
    int row_base = m0 + wm + mi * 16 + quad * 4;
    #pragma unroll
    for (int ni = 0; ni < NI; ni++) {
      int col_g = n0 + wn + ni * 16 + col;
      if (MODE == 1) {
        float* O = (float*)C;
        #pragma unroll
        for (int r = 0; r < 4; r++) O[(size_t)(row_base + r) * N + col_g] = acc[mi][ni][r];
      } else {  // MODE 3
        int region = col_g >> 10;  // 0,1: q ; 2: k ; 3: v
        if (region < 3) {
          int ri = (col_g & 127) >> 1;
          float sgn = (col_g & 1) ? 1.f : -1.f;
          unsigned short* qO = (unsigned short*)C;
          #pragma unroll
          for (int r = 0; r < 4; r++) {
            int row = row_base + r;
            int s = row & (S_LEN - 1);
            float cv = fc[s * 64 + ri], sv = fs[s * 64 + ri];
            float val = acc[mi][ni][r];
            float other = __shfl_xor(val, 1);
            float res = val * cv + sgn * other * sv;
            if (region < 2) qO[(size_t)row * 2048 + col_g] = f2bf(res * QSCALE);
            else            kb[(size_t)row * 1024 + (col_g - 2048)] = f2bf(res);
          }
        } else {
          int n_local = col_g - 3072;
          int b = row_base >> 11, s = row_base & (S_LEN - 1);
          int kvh = n_local >> 7, d = n_local & (HD - 1);
          ushort4 o4;
          o4.x = f2bf(acc[mi][ni][0]); o4.y = f2bf(acc[mi][ni][1]);
          o4.z = f2bf(acc[mi][ni][2]); o4.w = f2bf(acc[mi][ni][3]);
          *(ushort4*)(&vb[((size_t)((b * NKV + kvh) * HD + d)) * S_LEN + s]) = o4;
        }
      }
    }
  }
}

// ---------------- Flash attention, causal, GQA K/V ----------------
// Double-buffered K/V, ONE barrier per tile (round 13). 256-thread blocks
// (4 waves), ONE (b,h,q-tile) per block, grid (32,32), long-first dispatch.
// ROUND-14 PROBE: __builtin_amdgcn_sched_barrier(0) immediately after the
// prefetch-issue cluster. Hypothesis: the compiler sinks the `if (more)`
// global loads (uniform-branch region, only consumed at the loop tail) down
// to their LDS-write use site, serializing ~2x global-load latency into every
// tile. The fence pins the issue point at the iteration top. Correctness-
// neutral. If null, the loads were already hoisted and attn's ~2.5us/tile is
// chain-bound -> structure converged (remaining gap = T16 co-designed combo).
// NULL HYPOTHESES MEASURED on attn: barriers/tile 2->1 (r13), blocks/CU 2->3
// (r12), waves/block 8->4 (r12); VALU cuts +3us (r10).
// ROUND-11 LESSON (rule #20): prefetch state = NAMED scalars, never arrays.
// ROUND-8 LESSON: PLD multiple of 8. ROUND-9: linear layouts at bank floor.
// Guard: WRITE_SIZE ~16 MB (spill detector).
#define KLD 136   // 128 + 8
#define VLD 72    // 64 + 8
#define PLD 72    // multiple of 8
__global__ __launch_bounds__(256, 2) void k_attn(
    const unsigned short* __restrict__ q, const unsigned short* __restrict__ k,
    const unsigned short* __restrict__ vT, unsigned short* __restrict__ ao) {
  __shared__ __align__(16) unsigned short Ksm[2][64 * KLD];    // 34816 B
  __shared__ __align__(16) unsigned short Vsm[2][128 * VLD];   // 36864 B
  __shared__ __align__(16) unsigned short Psm[4 * 16 * PLD];   //  9216 B
  const int t = threadIdx.x;
  const int lane = t & 63, w = t >> 6;        // 4 waves
  const int col = lane & 15, quad = lane >> 4;
  const int bh = blockIdx.x;                  // b*NH + h
  const int b = bh >> 4, h = bh & 15;
  const int kvh = h >> 1;
  const int my_qt = 31 - blockIdx.y;          // long blocks launch FIRST
  const int qrow = my_qt * 64 + w * 16;       // this wave's 16 query rows
  unsigned short* Pw = &Psm[w * 16 * PLD];

  // staging: 4 uint4 per thread per matrix (256 threads)
  const int ki = t >> 4, kdc = t & 15;        // K row (+cc*16) / d-chunk
  const int vd = t >> 3, vkc = t & 7;         // V d-row (+cc*32) / key-chunk
  const unsigned short* kg = k + ((size_t)(b * S_LEN + ki)) * (NKV * HD) + kvh * HD + kdc * 8;
  const unsigned short* vg = vT + ((size_t)((b * NKV + kvh) * HD + vd)) * S_LEN + vkc * 8;
  const size_t KROW = (size_t)16 * (NKV * HD);    // +16 K rows
  const size_t VROW = (size_t)32 * S_LEN;         // +32 V d-rows
  const size_t KSTEP = (size_t)64 * (NKV * HD);   // shorts per K-tile
  const size_t VSTEP = 64;                        // shorts per V-tile

  bf16x8 qf[4];
  const size_t qbase = ((size_t)(b * S_LEN) + qrow + col) * DIM_ + h * HD;
  #pragma unroll
  for (int kc = 0; kc < 4; kc++) qf[kc] = *(const bf16x8*)(q + qbase + kc * 32 + quad * 8);

  f32x4 o[8];
  #pragma unroll
  for (int i = 0; i < 8; i++) o[i] = (f32x4){0.f, 0.f, 0.f, 0.f};
  float m_i = -1e30f;   // running max for q-row (qrow + col)
  float l_i = 0.f;      // running denom

  const int nkt = my_qt + 1;                  // block-uniform causal range

  // prologue: stage tile 0 into buffer 0
  {
    #pragma unroll
    for (int cc = 0; cc < 4; cc++) {
      uint4 kr = *(const uint4*)(kg + cc * KROW);
      *(uint4*)(&Ksm[0][(ki + cc * 16) * KLD + kdc * 8]) = kr;
      uint4 vr = *(const uint4*)(vg + cc * VROW);
      *(uint4*)(&Vsm[0][(vd + cc * 32) * VLD + vkc * 8]) = vr;
    }
  }
  __syncthreads();

  for (int kt = 0; kt < nkt; ++kt) {
    const int cur = kt & 1, nxt = cur ^ 1;
    const bool more = (kt + 1 < nkt);         // block-uniform
    // NAMED scalars (rule #20: arrays here get demoted to scratch)
    uint4 kr0, kr1, kr2, kr3, vr0, vr1, vr2, vr3;
    if (more) {                               // issue ALL t+1 loads early
      kg += KSTEP; vg += VSTEP;
      kr0 = *(const uint4*)(kg + 0 * KROW);
      kr1 = *(const uint4*)(kg + 1 * KROW);
      kr2 = *(const uint4*)(kg + 2 * KROW);
      kr3 = *(const uint4*)(kg + 3 * KROW);
      vr0 = *(const uint4*)(vg + 0 * VROW);
      vr1 = *(const uint4*)(vg + 1 * VROW);
      vr2 = *(const uint4*)(vg + 2 * VROW);
      vr3 = *(const uint4*)(vg + 3 * VROW);
    }
    // ROUND-14 PROBE: pin the prefetch issue HERE (prevent sinking to the
    // LDS-write site at the loop tail). Single fence, not per-instruction
    // pinning (m141 lesson).
    __builtin_amdgcn_sched_barrier(0);

    // ---- QK^T, swapped operands: p[nt][r] = P[key = kt*64+nt*16+quad*4+r][q = col]
    float p[4][4];
    __builtin_amdgcn_s_setprio(1);
    #pragma unroll
    for (int nt = 0; nt < 4; nt++) {
      f32x4 s_acc = (f32x4){0.f, 0.f, 0.f, 0.f};
      #pragma unroll
      for (int kc = 0; kc < 4; kc++) {
        bf16x8 kf = *(const bf16x8*)(&Ksm[cur][(nt * 16 + col) * KLD + kc * 32 + quad * 8]);
        s_acc = __builtin_amdgcn_mfma_f32_16x16x32_bf16(kf, qf[kc], s_acc, 0, 0, 0);
      }
      #pragma unroll
      for (int r = 0; r < 4; r++) p[nt][r] = s_acc[r];
    }
    __builtin_amdgcn_s_setprio(0);

    if (kt == my_qt) {  // diagonal tile: causal mask
      const int qglob = qrow + col;
      #pragma unroll
      for (int nt = 0; nt < 4; nt++)
        #pragma unroll
        for (int r = 0; r < 4; r++)
          if (kt * 64 + nt * 16 + quad * 4 + r > qglob) p[nt][r] = -1e30f;
    }

    // ---- softmax, speculative: exp2 with OLD m_i runs during the max shuffles
    float mx = fmaxf(fmaxf(fmaxf(p[0][0], p[0][1]), fmaxf(p[0][2], p[0][3])),
                     fmaxf(fmaxf(p[1][0], p[1][1]), fmaxf(p[1][2], p[1][3])));
    mx = fmaxf(mx, fmaxf(fmaxf(fmaxf(p[2][0], p[2][1]), fmaxf(p[2][2], p[2][3])),
                         fmaxf(fmaxf(p[3][0], p[3][1]), fmaxf(p[3][2], p[3][3]))));
    float mxs = fmaxf(mx, __shfl_xor(mx, 16));
    mxs = fmaxf(mxs, __shfl_xor(mxs, 32));
    float pe[4][4];
    #pragma unroll
    for (int nt = 0; nt < 4; nt++)
      #pragma unroll
      for (int r = 0; r < 4; r++) pe[nt][r] = exp2f(p[nt][r] - m_i);
    float rs = ((pe[0][0] + pe[0][1]) + (pe[0][2] + pe[0][3]))
             + ((pe[1][0] + pe[1][1]) + (pe[1][2] + pe[1][3]))
             + ((pe[2][0] + pe[2][1]) + (pe[2][2] + pe[2][3]))
             + ((pe[3][0] + pe[3][1]) + (pe[3][2] + pe[3][3]));
    if (__any(mxs - m_i > RESC_THR)) {   // rare: first tile + big max growth
      float mn = fmaxf(m_i, mxs);
      float alpha = exp2f(m_i - mn);
      m_i = mn; l_i *= alpha;
      float ar[4];
      #pragma unroll
      for (int r = 0; r < 4; r++) ar[r] = __shfl(alpha, quad * 4 + r);
      #pragma unroll
      for (int dt = 0; dt < 8; dt++)
        #pragma unroll
        for (int r = 0; r < 4; r++) o[dt][r] *= ar[r];
      #pragma unroll
      for (int nt = 0; nt < 4; nt++)
        #pragma unroll
        for (int r = 0; r < 4; r++) pe[nt][r] = exp2f(p[nt][r] - m_i);
      rs = ((pe[0][0] + pe[0][1]) + (pe[0][2] + pe[0][3]))
         + ((pe[1][0] + pe[1][1]) + (pe[1][2] + pe[1][3]))
         + ((pe[2][0] + pe[2][1]) + (pe[2][2] + pe[2][3]))
         + ((pe[3][0] + pe[3][1]) + (pe[3][2] + pe[3][3]));
    }
    rs += __shfl_xor(rs, 16);
    rs += __shfl_xor(rs, 32);
    l_i += rs;

    // ---- P -> Pw (A-layout: Pw[q][key]), cvt_pk pairs + uint2 writes
    #pragma unroll
    for (int nt = 0; nt < 4; nt++) {
      uint2 pk;
      pk.x = cvt_pk_bf16(pe[nt][0], pe[nt][1]);
      pk.y = cvt_pk_bf16(pe[nt][2], pe[nt][3]);
      *(uint2*)(&Pw[col * PLD + nt * 16 + quad * 4]) = pk;
    }
    asm volatile("s_waitcnt lgkmcnt(0)" ::: "memory");  // wave-internal RAW
    bf16x8 pf[2];
    #pragma unroll
    for (int kc2 = 0; kc2 < 2; kc2++)
      pf[kc2] = *(const bf16x8*)(&Pw[col * PLD + kc2 * 32 + quad * 8]);

    // ---- O += P V (reads Vsm[cur])
    __builtin_amdgcn_s_setprio(1);
    #pragma unroll
    for (int dt = 0; dt < 8; dt++) {
      #pragma unroll
      for (int kc2 = 0; kc2 < 2; kc2++) {
        bf16x8 vf = *(const bf16x8*)(&Vsm[cur][(dt * 16 + col) * VLD + kc2 * 32 + quad * 8]);
        o[dt] = __builtin_amdgcn_mfma_f32_16x16x32_bf16(pf[kc2], vf, o[dt], 0, 0, 0);
      }
    }
    __builtin_amdgcn_s_setprio(0);

    // ---- stage tile t+1 into the OTHER buffers (no wave reads them until
    //      after the barrier below; no wave is still in iteration t-1)
    if (more) {
      *(uint4*)(&Ksm[nxt][(ki +  0) * KLD + kdc * 8]) = kr0;
      *(uint4*)(&Ksm[nxt][(ki + 16) * KLD + kdc * 8]) = kr1;
      *(uint4*)(&Ksm[nxt][(ki + 32) * KLD + kdc * 8]) = kr2;
      *(uint4*)(&Ksm[nxt][(ki + 48) * KLD + kdc * 8]) = kr3;
      *(uint4*)(&Vsm[nxt][(vd +  0) * VLD + vkc * 8]) = vr0;
      *(uint4*)(&Vsm[nxt][(vd + 32) * VLD + vkc * 8]) = vr1;
      *(uint4*)(&Vsm[nxt][(vd + 64) * VLD + vkc * 8]) = vr2;
      *(uint4*)(&Vsm[nxt][(vd + 96) * VLD + vkc * 8]) = vr3;
    }

    __syncthreads();   // ONE barrier per tile: publishes buf[nxt], retires buf[cur]
  }

  // epilogue: 1/l for this lane's four q-rows (col -> row permute, once)
  float linv[4];
  #pragma unroll
  for (int r = 0; r < 4; r++) linv[r] = 1.f / __shfl(l_i, quad * 4 + r);
  #pragma unroll
  for (int dt = 0; dt < 8; dt++) {
    int dcol = h * HD + dt * 16 + col;
    #pragma unroll
    for (int r = 0; r < 4; r++) {
      int rg = qrow + quad * 4 + r;
      ao[((size_t)(b * S_LEN) + rg) * DIM_ + dcol] = f2bf(o[dt][r] * linv[r]);
    }
  }
}

extern "C" void kernel_launch(void* const* d_in, const int* in_sizes, int n_in,
                              void* d_out, int out_size, void* d_ws, size_t ws_size,
                              hipStream_t stream) {
  const float* x  = (const float*)d_in[0];
  const float* fc = (const float*)d_in[1];
  const float* fs = (const float*)d_in[2];
  const float* wq = (const float*)d_in[3];
  const float* wk = (const float*)d_in[4];
  const float* wv = (const float*)d_in[5];
  const float* wo = (const float*)d_in[6];
  float* out = (float*)d_out;

  char* ws = (char*)d_ws;
  const size_t MB = 1024 * 1024;
  unsigned short* xb    = (unsigned short*)(ws + 0 * MB);    // 4096x2048 bf16 (16 MiB)
  unsigned short* wqkvT = (unsigned short*)(ws + 16 * MB);   // 4096x2048      (16 MiB)
  unsigned short* woT   = (unsigned short*)(ws + 32 * MB);   // 2048x2048      (8 MiB)
  unsigned short* qb    = (unsigned short*)(ws + 40 * MB);   // 4096x2048      (16 MiB)
  unsigned short* kb    = (unsigned short*)(ws + 56 * MB);   // 4096x1024      (8 MiB)
  unsigned short* vT    = (unsigned short*)(ws + 64 * MB);   // (b,kvh,d,s)    (8 MiB)
  unsigned short* ao    = (unsigned short*)(ws + 72 * MB);   // 4096x2048      (16 MiB)

  // prep: convert x + transpose-convert all weights (vectorized 64x64 transpose)
  k_prep<<<dim3(11264), dim3(256), 0, stream>>>(x, xb, wq, wk, wv, wo, wqkvT, woT);
  // fused QKV projection + RoPE (+q pre-scale) + V transpose: 128sq, 4 blocks/CU (proven best)
  k_gemm_bt<3, 128, 256><<<dim3(32, 32), dim3(256), 0, stream>>>(xb, wqkvT, (void*)qb, 4096, 2048, fc, fs, kb, vT);
  // attention: double-buffered K/V, 1 barrier/tile, sched_barrier-pinned prefetch
  k_attn<<<dim3(32, 32), dim3(256), 0, stream>>>(qb, kb, vT, ao);
  // output projection (f32 out): 64x128 tiles -> grid (16,64) = 4 blocks/CU (round-4 proven)
  k_gemm_bt<1, 64, 256><<<dim3(16, 64), dim3(256), 0, stream>>>(ao, woT, (void*)out, 2048, 2048, nullptr, nullptr, nullptr, nullptr);
}

// Round 15
// 318.300 us; speedup vs baseline: 1.0629x; 1.0601x over previous
//
#include <hip/hip_runtime.h>
#include <cstdint>
#include <cstddef>

#define S_LEN 2048
#define DIM_   2048
#define NH   16
#define NKV  8
#define HD   128

typedef __attribute__((ext_vector_type(8))) __bf16 bf16x8;
typedef __attribute__((ext_vector_type(4))) float  f32x4;

typedef const __attribute__((address_space(1))) void* gptr_t;
typedef __attribute__((address_space(3))) void*       sptr_t;

static __device__ __forceinline__ float bf2f(unsigned short u) {
  union { unsigned int i; float f; } v; v.i = ((unsigned int)u) << 16; return v.f;
}
static __device__ __forceinline__ unsigned short f2bf(float f) {
  union { float f; unsigned int i; } v; v.f = f;
  unsigned int u = v.i;
  unsigned int r = (u + 0x7FFFu + ((u >> 16) & 1u)) >> 16;
  return (unsigned short)r;
}
// packed f32x2 -> bf16x2 (RNE), single instruction (T12 primitive)
static __device__ __forceinline__ unsigned int cvt_pk_bf16(float a, float b) {
  unsigned int r;
  asm volatile("v_cvt_pk_bf16_f32 %0, %1, %2" : "=v"(r) : "v"(a), "v"(b));
  return r;
}

// scale(1/sqrt(128)) * log2(e) — folded into q so softmax uses exp2 directly
#define QSCALE 0.12751744f
// defer-max threshold (T13): 8 in ln-domain -> 8*log2(e) in exp2-domain
#define RESC_THR 11.542f

// ---------------- prep: x->bf16 convert + 4 weight transpose-converts ----------------
// 64x64 tiles, float4 loads + packed ushort4 stores (round-7, proven).
__global__ void k_prep(const float* __restrict__ x, unsigned short* __restrict__ xb,
                       const float* __restrict__ wq, const float* __restrict__ wk,
                       const float* __restrict__ wv, const float* __restrict__ wo,
                       unsigned short* __restrict__ wqkvT, unsigned short* __restrict__ woT) {
  int bid = blockIdx.x;
  if (bid < 8192) {
    int i = bid * 256 + threadIdx.x;
    float4 v = ((const float4*)x)[i];
    ushort4 o; o.x = f2bf(v.x); o.y = f2bf(v.y); o.z = f2bf(v.z); o.w = f2bf(v.w);
    ((ushort4*)xb)[i] = o;
    return;
  }
  bid -= 8192;
  const float* src; unsigned short* dst; int N, ntx;
  if (bid < 1024)      { src = wq; dst = wqkvT;                       N = 2048; ntx = 32; }
  else if (bid < 1536) { bid -= 1024; src = wk; dst = wqkvT + (size_t)2048 * 2048; N = 1024; ntx = 16; }
  else if (bid < 2048) { bid -= 1536; src = wv; dst = wqkvT + (size_t)3072 * 2048; N = 1024; ntx = 16; }
  else                 { bid -= 2048; src = wo; dst = woT;            N = 2048; ntx = 32; }
  const int K = 2048;
  __shared__ float tile[64][65];
  int lx = threadIdx.x & 15, ly = threadIdx.x >> 4;  // 16 x 16
  int r0 = (bid / ntx) * 64, c0 = (bid % ntx) * 64;
  #pragma unroll
  for (int i = 0; i < 4; i++) {
    int row = ly + 16 * i;
    float4 v = *(const float4*)(&src[(size_t)(r0 + row) * N + c0 + lx * 4]);
    tile[row][lx * 4 + 0] = v.x; tile[row][lx * 4 + 1] = v.y;
    tile[row][lx * 4 + 2] = v.z; tile[row][lx * 4 + 3] = v.w;
  }
  __syncthreads();
  #pragma unroll
  for (int i = 0; i < 4; i++) {
    int nrow = ly + 16 * i;
    ushort4 o;
    o.x = f2bf(tile[lx * 4 + 0][nrow]); o.y = f2bf(tile[lx * 4 + 1][nrow]);
    o.z = f2bf(tile[lx * 4 + 2][nrow]); o.w = f2bf(tile[lx * 4 + 3][nrow]);
    *(ushort4*)(&dst[(size_t)(c0 + nrow) * K + r0 + lx * 4]) = o;
  }
}

// ------------- GEMM: C(MxN) = A(MxK) * BT(NxK)^T, bf16 in, fp32 acc -------------
// PROVEN 2-barrier template, generalized over <MODE, BM_, TPB>.
// BK=64, XOR-swizzled LDS via source permutation (bank-conflict 0 measured).
// TILE-SPACE MEASURED (MODE3): 128sq @4/CU = 84-87us BEST; 256x128 @2/CU = 100;
// 256sq @1/CU piped = 123. TLP dominates tile density in this structure.
// Structural ceiling: ~900 TF (m97-class); we measure 805 TF with the fused
// epilogue = 88%. Past it = faithful 8-phase port (needs race-screen infra).
template<int MODE, int BM_, int TPB>
__global__ __launch_bounds__(TPB, 2) void k_gemm_bt(
    const unsigned short* __restrict__ A, const unsigned short* __restrict__ BT,
    void* __restrict__ C, int N, int K,
    const float* __restrict__ fc, const float* __restrict__ fs,
    unsigned short* __restrict__ kb, unsigned short* __restrict__ vb) {
  constexpr int NI = (BM_ == 64) ? 2 : 4;          // B-frags per wave
  constexpr int AR = (BM_ * 64) / (TPB * 8);       // A staging rounds
  constexpr int BR = (128 * 64) / (TPB * 8);       // B staging rounds
  __shared__ __align__(16) unsigned short Asm[BM_ * 64];
  __shared__ __align__(16) unsigned short Bsm[128 * 64];
  const int t = threadIdx.x;
  const int lane = t & 63, w = t >> 6;
  const int wm = (BM_ == 64) ? 0 : (w >> 1) * 64;
  const int wn = (BM_ == 64) ? w * 32 : (w & 1) * 64;
  const int col = lane & 15, quad = lane >> 4;
  const int m0 = blockIdx.y * BM_, n0 = blockIdx.x * 128;

  f32x4 acc[4][NI];
  #pragma unroll
  for (int i = 0; i < 4; i++)
    #pragma unroll
    for (int j = 0; j < NI; j++) acc[i][j] = (f32x4){0.f, 0.f, 0.f, 0.f};

  for (int kk = 0; kk < K; kk += 64) {
    #pragma unroll
    for (int r = 0; r < AR; ++r) {   // A: BM_ rows x 64
      int c = t + r * TPB;
      int c0 = (t & ~63) + r * TPB;   // wave-uniform chunk base
      int row = c >> 3;
      int kcs = (c & 7) ^ (row & 7);  // source permutation = target swizzle
      const unsigned short* gA = A + (size_t)(m0 + row) * K + kk + kcs * 8;
      __builtin_amdgcn_global_load_lds((gptr_t)gA, (sptr_t)(&Asm[c0 * 8]), 16, 0, 0);
    }
    #pragma unroll
    for (int r = 0; r < BR; ++r) {   // B: 128 rows x 64
      int c = t + r * TPB;
      int c0 = (t & ~63) + r * TPB;
      int row = c >> 3;
      int kcs = (c & 7) ^ (row & 7);
      const unsigned short* gB = BT + (size_t)(n0 + row) * K + kk + kcs * 8;
      __builtin_amdgcn_global_load_lds((gptr_t)gB, (sptr_t)(&Bsm[c0 * 8]), 16, 0, 0);
    }
    __syncthreads();
    #pragma unroll
    for (int kc2 = 0; kc2 < 2; kc2++) {
      bf16x8 af[4], bf[NI];
      #pragma unroll
      for (int mi = 0; mi < 4; mi++) {
        int rowA = wm + mi * 16 + col;
        af[mi] = *(const bf16x8*)(&Asm[rowA * 64 + (((kc2 * 4 + quad) ^ (col & 7)) * 8)]);
      }
      #pragma unroll
      for (int ni = 0; ni < NI; ni++) {
        int rowB = wn + ni * 16 + col;
        bf[ni] = *(const bf16x8*)(&Bsm[rowB * 64 + (((kc2 * 4 + quad) ^ (col & 7)) * 8)]);
      }
      #pragma unroll
      for (int mi = 0; mi < 4; mi++)
        #pragma unroll
        for (int ni = 0; ni < NI; ni++)
          acc[mi][ni] = __builtin_amdgcn_mfma_f32_16x16x32_bf16(af[mi], bf[ni], acc[mi][ni], 0, 0, 0);
    }
    __syncthreads();
  }

  #pragma unroll
  for (int mi = 0; mi < 4; mi++) {
    int row_base = m0 + wm + mi * 16 + quad * 4;
    #pragma unroll
    for (int ni = 0; ni < NI; ni++) {
      int col_g = n0 + wn + ni * 16 + col;
      if (MODE == 1) {
        float* O = (float*)C;
        #pragma unroll
        for (int r = 0; r < 4; r++) O[(size_t)(row_base + r) * N + col_g] = acc[mi][ni][r];
      } else {  // MODE 3
        int region = col_g >> 10;  // 0,1: q ; 2: k ; 3: v
        if (region < 3) {
          int ri = (col_g & 127) >> 1;
          float sgn = (col_g & 1) ? 1.f : -1.f;
          unsigned short* qO = (unsigned short*)C;
          #pragma unroll
          for (int r = 0; r < 4; r++) {
            int row = row_base + r;
            int s = row & (S_LEN - 1);
            float cv = fc[s * 64 + ri], sv = fs[s * 64 + ri];
            float val = acc[mi][ni][r];
            float other = __shfl_xor(val, 1);
            float res = val * cv + sgn * other * sv;
            if (region < 2) qO[(size_t)row * 2048 + col_g] = f2bf(res * QSCALE);
            else            kb[(size_t)row * 1024 + (col_g - 2048)] = f2bf(res);
          }
        } else {
          int n_local = col_g - 3072;
          int b = row_base >> 11, s = row_base & (S_LEN - 1);
          int kvh = n_local >> 7, d = n_local & (HD - 1);
          ushort4 o4;
          o4.x = f2bf(acc[mi][ni][0]); o4.y = f2bf(acc[mi][ni][1]);
          o4.z = f2bf(acc[mi][ni][2]); o4.w = f2bf(acc[mi][ni][3]);
          *(ushort4*)(&vb[((size_t)((b * NKV + kvh) * HD + d)) * S_LEN + s]) = o4;
        }
      }
    }
  }
}

// ---------------- Flash attention, causal, GQA-shared K/V ----------------
// TERMINAL CONFIG (round-10 artifact, best-measured total 327.6us).
// 512-thread blocks (8 waves = 2 heads x 4 waves), ONE q-tile per block,
// grid (16,32) = 2 blocks/CU, yi-paired load balance. Swapped QK^T (lane owns
// a q-row), async K/V staging (T14, named scalars), defer-max (T13), setprio
// (T5), cvt_pk P-packing, speculative exp2, strength-reduced pointers.
// PROBE MATRIX (all measured, all null -> structure converged):
//   barriers/tile 2->1 (r13), blocks/CU 2->3 (r12), waves/block 8->4 (r12),
//   sched_barrier prefetch pin (r14). VALU cuts +3us (r10).
// Remaining gap = T16/8-phase co-designed sync structures (need race-screen).
// ROUND-8 LESSON: PLD must be multiple of 8 (16B-aligned b128 reads).
// ROUND-9 LESSON: linear K/V/P layouts are at the bank floor; do not swizzle.
// ROUND-11 LESSON (rule #20): prefetch state = NAMED scalars, never arrays.
// ROUND-1 LESSON: __launch_bounds__ 2nd arg acts as BLOCKS/CU; keep (512,2).
#define KLD 136   // 128 + 8 (row-to-row bank offset 4 -> conflict-free frags)
#define VLD 72    // 64 + 8
#define PLD 72    // MUST stay multiple of 8 (16B-aligned b128 reads)
__global__ __launch_bounds__(512, 2) void k_attn(
    const unsigned short* __restrict__ q, const unsigned short* __restrict__ k,
    const unsigned short* __restrict__ vT, unsigned short* __restrict__ ao) {
  __shared__ __align__(16) unsigned short Ksm[64 * KLD];       // 17408 B
  __shared__ __align__(16) unsigned short Vsm[128 * VLD];      // 18432 B
  __shared__ __align__(16) unsigned short Psm[8 * 16 * PLD];   // 18432 B
  const int t = threadIdx.x;
  const int lane = t & 63, w = t >> 6;        // 8 waves
  const int col = lane & 15, quad = lane >> 4;
  const int g = blockIdx.x;                   // b*NKV + kvh
  const int b = g >> 3, kvh = g & 7;
  const int h = kvh * 2 + (w >> 2);           // waves 0-3: head 2g, 4-7: head 2g+1
  const int yi = blockIdx.y;                  // 0..31
  const int my_qt = (yi < 16) ? yi : 47 - yi; // balanced long/short pairing
  const int qrow = my_qt * 64 + (w & 3) * 16; // this wave's 16 query rows
  unsigned short* Pw = &Psm[w * 16 * PLD];

  // staging addresses: strength-reduced running pointers (+= const per tile)
  const int ki0 = t >> 4,        kdc = t & 15;         // K row / d-chunk
  const int ki1 = (t + 512) >> 4;
  const int vd0 = t >> 3,        vkc = t & 7;          // V d-row / key-chunk
  const int vd1 = (t + 512) >> 3;
  const unsigned short* kg0 = k + ((size_t)(b * S_LEN + ki0)) * (NKV * HD) + kvh * HD + kdc * 8;
  const unsigned short* kg1 = k + ((size_t)(b * S_LEN + ki1)) * (NKV * HD) + kvh * HD + kdc * 8;
  const unsigned short* vg0 = vT + ((size_t)((b * NKV + kvh) * HD + vd0)) * S_LEN + vkc * 8;
  const unsigned short* vg1 = vT + ((size_t)((b * NKV + kvh) * HD + vd1)) * S_LEN + vkc * 8;
  const size_t KSTEP = (size_t)64 * (NKV * HD);   // shorts per K-tile
  const size_t VSTEP = 64;                        // shorts per V-tile

  bf16x8 qf[4];
  const size_t qbase = ((size_t)(b * S_LEN) + qrow + col) * DIM_ + h * HD;
  #pragma unroll
  for (int kc = 0; kc < 4; kc++) qf[kc] = *(const bf16x8*)(q + qbase + kc * 32 + quad * 8);

  f32x4 o[8];
  #pragma unroll
  for (int i = 0; i < 8; i++) o[i] = (f32x4){0.f, 0.f, 0.f, 0.f};
  float m_i = -1e30f;   // running max for q-row (qrow + col)
  float l_i = 0.f;      // running denom for q-row (qrow + col)

  const int nkt = my_qt + 1;                  // wave-uniform causal range

  // prologue: stage tile 0
  {
    uint4 kr0 = *(const uint4*)kg0;
    uint4 kr1 = *(const uint4*)kg1;
    uint4 vr0 = *(const uint4*)vg0;
    uint4 vr1 = *(const uint4*)vg1;
    *(uint4*)(&Ksm[ki0 * KLD + kdc * 8]) = kr0;
    *(uint4*)(&Ksm[ki1 * KLD + kdc * 8]) = kr1;
    *(uint4*)(&Vsm[vd0 * VLD + vkc * 8]) = vr0;
    *(uint4*)(&Vsm[vd1 * VLD + vkc * 8]) = vr1;
  }
  __syncthreads();

  for (int kt = 0; kt < nkt; ++kt) {
    const bool more = (kt + 1 < nkt);         // block-uniform
    uint4 kr0, kr1, vr0, vr1;
    if (more) {                               // issue K(t+1) early: latency hides under QK+softmax
      kg0 += KSTEP; kg1 += KSTEP;
      kr0 = *(const uint4*)kg0;
      kr1 = *(const uint4*)kg1;
    }

    // ---- QK^T, swapped operands: p[nt][r] = P[key = kt*64+nt*16+quad*4+r][q = col]
    float p[4][4];
    __builtin_amdgcn_s_setprio(1);
    #pragma unroll
    for (int nt = 0; nt < 4; nt++) {
      f32x4 s_acc = (f32x4){0.f, 0.f, 0.f, 0.f};
      #pragma unroll
      for (int kc = 0; kc < 4; kc++) {
        bf16x8 kf = *(const bf16x8*)(&Ksm[(nt * 16 + col) * KLD + kc * 32 + quad * 8]);
        s_acc = __builtin_amdgcn_mfma_f32_16x16x32_bf16(kf, qf[kc], s_acc, 0, 0, 0);
      }
      #pragma unroll
      for (int r = 0; r < 4; r++) p[nt][r] = s_acc[r];
    }
    __builtin_amdgcn_s_setprio(0);

    if (kt == my_qt) {  // diagonal tile: causal mask (q = qrow+col, key per reg)
      const int qglob = qrow + col;
      #pragma unroll
      for (int nt = 0; nt < 4; nt++)
        #pragma unroll
        for (int r = 0; r < 4; r++)
          if (kt * 64 + nt * 16 + quad * 4 + r > qglob) p[nt][r] = -1e30f;
    }

    // ---- softmax, speculative: exp2 with OLD m_i runs during the max shuffles
    float mx = fmaxf(fmaxf(fmaxf(p[0][0], p[0][1]), fmaxf(p[0][2], p[0][3])),
                     fmaxf(fmaxf(p[1][0], p[1][1]), fmaxf(p[1][2], p[1][3])));
    mx = fmaxf(mx, fmaxf(fmaxf(fmaxf(p[2][0], p[2][1]), fmaxf(p[2][2], p[2][3])),
                         fmaxf(fmaxf(p[3][0], p[3][1]), fmaxf(p[3][2], p[3][3]))));
    float mxs = fmaxf(mx, __shfl_xor(mx, 16));
    mxs = fmaxf(mxs, __shfl_xor(mxs, 32));
    // speculative (independent of the shuffles above -> scheduler overlaps)
    float pe[4][4];
    #pragma unroll
    for (int nt = 0; nt < 4; nt++)
      #pragma unroll
      for (int r = 0; r < 4; r++) pe[nt][r] = exp2f(p[nt][r] - m_i);
    float rs = ((pe[0][0] + pe[0][1]) + (pe[0][2] + pe[0][3]))
             + ((pe[1][0] + pe[1][1]) + (pe[1][2] + pe[1][3]))
             + ((pe[2][0] + pe[2][1]) + (pe[2][2] + pe[2][3]))
             + ((pe[3][0] + pe[3][1]) + (pe[3][2] + pe[3][3]));
    if (__any(mxs - m_i > RESC_THR)) {   // rare: first tile + big max growth
      float mn = fmaxf(m_i, mxs);
      float alpha = exp2f(m_i - mn);
      m_i = mn; l_i *= alpha;
      float ar[4];
      #pragma unroll
      for (int r = 0; r < 4; r++) ar[r] = __shfl(alpha, quad * 4 + r);
      #pragma unroll
      for (int dt = 0; dt < 8; dt++)
        #pragma unroll
        for (int r = 0; r < 4; r++) o[dt][r] *= ar[r];
      #pragma unroll
      for (int nt = 0; nt < 4; nt++)
        #pragma unroll
        for (int r = 0; r < 4; r++) pe[nt][r] = exp2f(p[nt][r] - m_i);
      rs = ((pe[0][0] + pe[0][1]) + (pe[0][2] + pe[0][3]))
         + ((pe[1][0] + pe[1][1]) + (pe[1][2] + pe[1][3]))
         + ((pe[2][0] + pe[2][1]) + (pe[2][2] + pe[2][3]))
         + ((pe[3][0] + pe[3][1]) + (pe[3][2] + pe[3][3]));
    }
    rs += __shfl_xor(rs, 16);
    rs += __shfl_xor(rs, 32);
    l_i += rs;

    // ---- P -> Pw (A-layout: Pw[q][key]), cvt_pk pairs + uint2 writes
    #pragma unroll
    for (int nt = 0; nt < 4; nt++) {
      uint2 pk;
      pk.x = cvt_pk_bf16(pe[nt][0], pe[nt][1]);
      pk.y = cvt_pk_bf16(pe[nt][2], pe[nt][3]);
      *(uint2*)(&Pw[col * PLD + nt * 16 + quad * 4]) = pk;
    }

    __syncthreads();   // B1: all waves done reading Ksm (and Pw writes drained)

    if (more) {        // K(t+1) -> LDS (overlaps PV), issue V(t+1) loads
      *(uint4*)(&Ksm[ki0 * KLD + kdc * 8]) = kr0;
      *(uint4*)(&Ksm[ki1 * KLD + kdc * 8]) = kr1;
      vg0 += VSTEP; vg1 += VSTEP;
      vr0 = *(const uint4*)vg0;
      vr1 = *(const uint4*)vg1;
    }

    bf16x8 pf[2];
    #pragma unroll
    for (int kc2 = 0; kc2 < 2; kc2++)
      pf[kc2] = *(const bf16x8*)(&Pw[col * PLD + kc2 * 32 + quad * 8]);

    // ---- O += P V
    __builtin_amdgcn_s_setprio(1);
    #pragma unroll
    for (int dt = 0; dt < 8; dt++) {
      #pragma unroll
      for (int kc2 = 0; kc2 < 2; kc2++) {
        bf16x8 vf = *(const bf16x8*)(&Vsm[(dt * 16 + col) * VLD + kc2 * 32 + quad * 8]);
        o[dt] = __builtin_amdgcn_mfma_f32_16x16x32_bf16(pf[kc2], vf, o[dt], 0, 0, 0);
      }
    }
    __builtin_amdgcn_s_setprio(0);

    __syncthreads();   // B2: all waves done reading Vsm; Ksm(t+1) visible

    if (more) {        // V(t+1) -> LDS (overlaps next QK)
      *(uint4*)(&Vsm[vd0 * VLD + vkc * 8]) = vr0;
      *(uint4*)(&Vsm[vd1 * VLD + vkc * 8]) = vr1;
    }
  }

  // epilogue: 1/l for this lane's four q-rows (col -> row permute, once)
  float linv[4];
  #pragma unroll
  for (int r = 0; r < 4; r++) linv[r] = 1.f / __shfl(l_i, quad * 4 + r);
  #pragma unroll
  for (int dt = 0; dt < 8; dt++) {
    int dcol = h * HD + dt * 16 + col;
    #pragma unroll
    for (int r = 0; r < 4; r++) {
      int rg = qrow + quad * 4 + r;
      ao[((size_t)(b * S_LEN) + rg) * DIM_ + dcol] = f2bf(o[dt][r] * linv[r]);
    }
  }
}

extern "C" void kernel_launch(void* const* d_in, const int* in_sizes, int n_in,
                              void* d_out, int out_size, void* d_ws, size_t ws_size,
                              hipStream_t stream) {
  const float* x  = (const float*)d_in[0];
  const float* fc = (const float*)d_in[1];
  const float* fs = (const float*)d_in[2];
  const float* wq = (const float*)d_in[3];
  const float* wk = (const float*)d_in[4];
  const float* wv = (const float*)d_in[5];
  const float* wo = (const float*)d_in[6];
  float* out = (float*)d_out;

  char* ws = (char*)d_ws;
  const size_t MB = 1024 * 1024;
  unsigned short* xb    = (unsigned short*)(ws + 0 * MB);    // 4096x2048 bf16 (16 MiB)
  unsigned short* wqkvT = (unsigned short*)(ws + 16 * MB);   // 4096x2048      (16 MiB)
  unsigned short* woT   = (unsigned short*)(ws + 32 * MB);   // 2048x2048      (8 MiB)
  unsigned short* qb    = (unsigned short*)(ws + 40 * MB);   // 4096x2048      (16 MiB)
  unsigned short* kb    = (unsigned short*)(ws + 56 * MB);   // 4096x1024      (8 MiB)
  unsigned short* vT    = (unsigned short*)(ws + 64 * MB);   // (b,kvh,d,s)    (8 MiB)
  unsigned short* ao    = (unsigned short*)(ws + 72 * MB);   // 4096x2048      (16 MiB)

  // prep: convert x + transpose-convert all weights (vectorized 64x64 transpose)
  k_prep<<<dim3(11264), dim3(256), 0, stream>>>(x, xb, wq, wk, wv, wo, wqkvT, woT);
  // fused QKV projection + RoPE (+q pre-scale) + V transpose: 128sq, 4 blocks/CU (proven best)
  k_gemm_bt<3, 128, 256><<<dim3(32, 32), dim3(256), 0, stream>>>(xb, wqkvT, (void*)qb, 4096, 2048, fc, fs, kb, vT);
  // attention: swapped-QK softmax (speculative exp2) + async staging (round-10 best artifact)
  k_attn<<<dim3(16, 32), dim3(512), 0, stream>>>(qb, kb, vT, ao);
  // output projection (f32 out): 64x128 tiles -> grid (16,64) = 4 blocks/CU (round-4 proven)
  k_gemm_bt<1, 64, 256><<<dim3(16, 64), dim3(256), 0, stream>>>(ao, woT, (void*)out, 2048, 2048, nullptr, nullptr, nullptr, nullptr);
}